// Round 14
// baseline (301.009 us; speedup 1.0000x reference)
//
#include <hip/hip_runtime.h>

#define NN 100000
#define NE 1600000
// DIM_IN = DIM_H = 128, DIM_OUT = 64
#define NN16 ((size_t)NN * 16)   // shorts per column-group slice

typedef __attribute__((ext_vector_type(8))) short bf16x8;   // 8 bf16 = 4 VGPR
typedef __attribute__((ext_vector_type(4))) float f32x4;

__device__ __forceinline__ float bf2f(unsigned short b) {
    union { unsigned int u; float f; } v;
    v.u = ((unsigned int)b) << 16;
    return v.f;
}
__device__ __forceinline__ unsigned short f2bf(float f) {
    union { float f; unsigned int u; } v; v.f = f;
    unsigned int u = v.u;
    return (unsigned short)((u + 0x7FFFu + ((u >> 16) & 1u)) >> 16);  // RNE
}

// ---------------------------------------------------------------------------
// edge_index dtype detect: int64 -> high words all 0; int32 -> odd words are
// random node ids (nonzero w.p. ~1). flag: 0 = int64, 1 = int32.
// ---------------------------------------------------------------------------
__global__ void detect_kernel(const int* __restrict__ e, int* __restrict__ flag) {
    int t = blockIdx.x * blockDim.x + threadIdx.x;
    if (t < 4096 && e[2 * t + 1] != 0) atomicOr(flag, 1);
}

__device__ __forceinline__ int esrc(const int* e, int mode, int i) {
    return mode ? e[i] : e[2 * i];
}
__device__ __forceinline__ int edst(const int* e, int mode, int i) {
    return mode ? e[NE + i] : e[2 * (NE + i)];
}

// ---------------------------------------------------------------------------
// LDS counting-sort CSR build (zero global atomics). Block (r,c) = dst-range r
// (25000 nodes, 100KB LDS) x edge-chunk c. Pass A: LDS hist -> G[c][d].
// Pass C: re-scan chunk, scatter via csr[atomicAdd(&sOff[dl],1)], sOff = S+G.
// ---------------------------------------------------------------------------
#define NRANGE 4
#define RSZ 25000
#define NCHUNK 64
#define EPC (NE / NCHUNK)
#define GS 100352

__global__ __launch_bounds__(1024) void histA_kernel(
    const int* __restrict__ e, const int* __restrict__ flag, int* __restrict__ G) {
    __shared__ int lh[RSZ];
    const int bid = blockIdx.x;
    const int r = bid & (NRANGE - 1);
    const int c = bid >> 2;
    const int lo = r * RSZ;
    for (int idx = threadIdx.x; idx < RSZ; idx += 1024) lh[idx] = 0;
    __syncthreads();
    const int mode = *flag;
    const int base = c * EPC;
    for (int i = base + threadIdx.x; i < base + EPC; i += 1024) {
        int dl = edst(e, mode, i) - lo;
        if ((unsigned)dl < (unsigned)RSZ) atomicAdd(&lh[dl], 1);
    }
    __syncthreads();
    for (int idx = threadIdx.x; idx < RSZ; idx += 1024)
        G[(size_t)c * GS + lo + idx] = lh[idx];
}

__global__ __launch_bounds__(1024) void scatterC_kernel(
    const int* __restrict__ e, const int* __restrict__ flag,
    const int* __restrict__ S, const int* __restrict__ G, int* __restrict__ csr) {
    __shared__ int sOff[RSZ];
    const int bid = blockIdx.x;
    const int r = bid & (NRANGE - 1);
    const int c = bid >> 2;
    const int lo = r * RSZ;
    for (int idx = threadIdx.x; idx < RSZ; idx += 1024)
        sOff[idx] = S[lo + idx] + G[(size_t)c * GS + lo + idx];
    __syncthreads();
    const int mode = *flag;
    const int base = c * EPC;
    for (int i = base + threadIdx.x; i < base + EPC; i += 1024) {
        int dl = edst(e, mode, i) - lo;
        if ((unsigned)dl < (unsigned)RSZ) {
            int s = esrc(e, mode, i);
            csr[atomicAdd(&sOff[dl], 1)] = s;
        }
    }
}

// ---------------------------------------------------------------------------
// Kernel B: per-node exclusive prefix of G over the 64 chunks, deg -> S.
// f32->bf16 convert of x into COLUMN-BLOCKED xb [8][NN][16] fused in.
// ---------------------------------------------------------------------------
#define PREF_B 391
#define CVT_G 6250  // 6250*256 threads x 1 16B-chunk = NN*16 chunks

__global__ __launch_bounds__(256) void prefix_cvt_kernel(
    int* __restrict__ G, int* __restrict__ S,
    const float* __restrict__ xin, unsigned short* __restrict__ xb) {
    if (blockIdx.x < PREF_B) {
        int d = blockIdx.x * 256 + threadIdx.x;
        if (d >= NN) return;
        int run = 0;
#pragma unroll 8
        for (int c = 0; c < NCHUNK; c++) {
            size_t idx = (size_t)c * GS + d;
            int t = G[idx];
            G[idx] = run;
            run += t;
        }
        S[d] = run;  // in-degree
    } else {
        long long i = (long long)(blockIdx.x - PREF_B) * 256 + threadIdx.x;
        int n = (int)(i >> 4);
        int chunk = (int)(i & 15);          // 8-col chunk within the row
        int g = chunk >> 1, off = (chunk & 1) * 8;
        const float* src = xin + (size_t)n * 128 + chunk * 8;
        float4 a = *(const float4*)(src);
        float4 b = *(const float4*)(src + 4);
        bf16x8 rv;
        rv[0] = (short)f2bf(a.x); rv[1] = (short)f2bf(a.y);
        rv[2] = (short)f2bf(a.z); rv[3] = (short)f2bf(a.w);
        rv[4] = (short)f2bf(b.x); rv[5] = (short)f2bf(b.y);
        rv[6] = (short)f2bf(b.z); rv[7] = (short)f2bf(b.w);
        *(bf16x8*)(xb + (size_t)g * NN16 + (size_t)n * 16 + off) = rv;
    }
}

// ---------------------------------------------------------------------------
// 3-phase exclusive scan of S[0..NN). S becomes the global exclusive prefix.
// ---------------------------------------------------------------------------
#define SCAN_G 392

__global__ __launch_bounds__(256) void blocksum_kernel(const int* __restrict__ S,
                                                       int* __restrict__ part) {
    int i = blockIdx.x * 256 + threadIdx.x;
    int v = (i < NN) ? S[i] : 0;
#pragma unroll
    for (int off = 32; off; off >>= 1) v += __shfl_down(v, off, 64);
    __shared__ int wsum[4];
    if ((threadIdx.x & 63) == 0) wsum[threadIdx.x >> 6] = v;
    __syncthreads();
    if (threadIdx.x == 0)
        part[blockIdx.x] = wsum[0] + wsum[1] + wsum[2] + wsum[3];
}

__global__ __launch_bounds__(512) void partscan_kernel(int* __restrict__ part) {
    __shared__ int lds[512];
    const int t = threadIdx.x;
    int v = (t < SCAN_G) ? part[t] : 0;
    lds[t] = v;
    __syncthreads();
    for (int off = 1; off < 512; off <<= 1) {
        int u = (t >= off) ? lds[t - off] : 0;
        __syncthreads();
        lds[t] += u;
        __syncthreads();
    }
    if (t < SCAN_G) part[t] = lds[t] - v;  // exclusive
}

__global__ __launch_bounds__(256) void scanfin_kernel(int* __restrict__ S,
                                                      const int* __restrict__ part) {
    __shared__ int lds[256];
    const int t = threadIdx.x;
    const int i = blockIdx.x * 256 + t;
    int v = (i < NN) ? S[i] : 0;
    lds[t] = v;
    __syncthreads();
    for (int off = 1; off < 256; off <<= 1) {
        int u = (t >= off) ? lds[t - off] : 0;
        __syncthreads();
        lds[t] += u;
        __syncthreads();
    }
    if (i < NN) S[i] = lds[t] - v + part[blockIdx.x];  // exclusive + block offset
}

// ---------------------------------------------------------------------------
// Column-blocked gather-mean, layer 1. xb/mean1 are [8][NN][16] blocked.
// Block's colgroup g = blockIdx&7 -> pinned to one XCD (m09 round-robin), so
// each XCD's L2 holds only its 3.2MB column slice (vs re-fetching all 25.6MB).
// 8 lanes/node: bit0 = col half (16B), bits1-2 = neighbor slot (4-way MLP);
// shfl_xor reduce over slots. csr NT-loads / output NT-stores protect the
// L2-resident slice. Correct for ANY block->XCD mapping (perf-only).
// ---------------------------------------------------------------------------
__global__ __launch_bounds__(256) void gather128_col(
    const unsigned short* __restrict__ xb, const int* __restrict__ csr,
    const int* __restrict__ S, unsigned short* __restrict__ mean1) {
    const int g = blockIdx.x & 7;
    const int q = blockIdx.x >> 3;
    const int lane8 = threadIdx.x & 7;
    const int node = q * 32 + (threadIdx.x >> 3);
    if (node >= NN) return;
    const int half = lane8 & 1;
    const int slot = lane8 >> 1;
    const int begin = S[node];
    const int end = (node == NN - 1) ? NE : S[node + 1];
    const unsigned short* base = xb + (size_t)g * NN16 + half * 8;
    float acc0[8] = {0.f, 0.f, 0.f, 0.f, 0.f, 0.f, 0.f, 0.f};
    float acc1[8] = {0.f, 0.f, 0.f, 0.f, 0.f, 0.f, 0.f, 0.f};
    int j = begin + slot;
    for (; j + 4 < end; j += 8) {
        int s0 = __builtin_nontemporal_load(csr + j);
        int s1 = __builtin_nontemporal_load(csr + j + 4);
        bf16x8 v0 = *(const bf16x8*)(base + (size_t)s0 * 16);
        bf16x8 v1 = *(const bf16x8*)(base + (size_t)s1 * 16);
#pragma unroll
        for (int p = 0; p < 8; p++) {
            acc0[p] += bf2f((unsigned short)v0[p]);
            acc1[p] += bf2f((unsigned short)v1[p]);
        }
    }
    if (j < end) {
        int s = __builtin_nontemporal_load(csr + j);
        bf16x8 v = *(const bf16x8*)(base + (size_t)s * 16);
#pragma unroll
        for (int p = 0; p < 8; p++) acc0[p] += bf2f((unsigned short)v[p]);
    }
#pragma unroll
    for (int p = 0; p < 8; p++) {
        float a = acc0[p] + acc1[p];
        a += __shfl_xor(a, 2, 64);
        a += __shfl_xor(a, 4, 64);
        acc0[p] = a;
    }
    if (slot == 0) {
        const float inv = 1.0f / fmaxf((float)(end - begin), 1.0f);
        bf16x8 r;
#pragma unroll
        for (int p = 0; p < 8; p++) r[p] = (short)f2bf(acc0[p] * inv);
        __builtin_nontemporal_store(
            r, (bf16x8*)(mean1 + (size_t)g * NN16 + (size_t)node * 16 + half * 8));
    }
}

// ---------------------------------------------------------------------------
// GEMM 1 (round-10-proven W-in-LDS): h = relu(mean1@W_l1 + x@W_r1 + b1).
// A/X/H in column-blocked layout (16-row col-slices are contiguous 512B ->
// better coalescing than row-major). W^T staged to LDS pitch 136.
// C/D layout: col=lane&15, row=(lane>>4)*4+reg.
// ---------------------------------------------------------------------------
__global__ __launch_bounds__(256, 2) void gemm1_kernel(
    const unsigned short* __restrict__ A,   // mean1 blocked [8][NN][16]
    const unsigned short* __restrict__ X,   // xb blocked [8][NN][16]
    const float* __restrict__ Wa,           // W_l1 [128][128] f32
    const float* __restrict__ Wb,           // W_r1 [128][128] f32
    const float* __restrict__ b1,
    unsigned short* __restrict__ H,         // blocked [8][NN][16]
    int N) {
    constexpr int PITCH = 136;
    __shared__ unsigned short sWa[128 * PITCH];
    __shared__ unsigned short sWb[128 * PITCH];
    const int tid = threadIdx.x;
    for (int idx = tid; idx < 128 * 128; idx += 256) {
        int k = idx >> 7, n = idx & 127;
        sWa[n * PITCH + k] = f2bf(Wa[idx]);
        sWb[n * PITCH + k] = f2bf(Wb[idx]);
    }
    __syncthreads();

    const int lane = tid & 63;
    const int wv = tid >> 6;
    const int r16 = lane & 15;
    const int kg = lane >> 4;
    const long long rowbase = (long long)blockIdx.x * 128 + wv * 32;

    bf16x8 xf[2][4], af[2][4];
    const bf16x8 zz = {0, 0, 0, 0, 0, 0, 0, 0};
#pragma unroll
    for (int rt = 0; rt < 2; rt++) {
        long long row = rowbase + rt * 16 + r16;
        bool ok = row < N;
#pragma unroll
        for (int ks = 0; ks < 4; ks++) {
            size_t off = (size_t)(2 * ks + (kg >> 1)) * NN16 + (size_t)row * 16 + (kg & 1) * 8;
            xf[rt][ks] = ok ? *(const bf16x8*)(X + off) : zz;
            af[rt][ks] = ok ? *(const bf16x8*)(A + off) : zz;
        }
    }

    f32x4 acc[2][8];
#pragma unroll
    for (int t = 0; t < 8; t++) {
        float bv = b1[t * 16 + r16];
#pragma unroll
        for (int rt = 0; rt < 2; rt++) acc[rt][t] = (f32x4){bv, bv, bv, bv};
    }

#pragma unroll
    for (int t = 0; t < 8; t++) {
        const unsigned short* wp = &sWb[(t * 16 + r16) * PITCH + kg * 8];
        const unsigned short* wq = &sWa[(t * 16 + r16) * PITCH + kg * 8];
        bf16x8 bb[4], ba[4];
#pragma unroll
        for (int ks = 0; ks < 4; ks++) {
            bb[ks] = *(const bf16x8*)(wp + ks * 32);
            ba[ks] = *(const bf16x8*)(wq + ks * 32);
        }
#pragma unroll
        for (int rt = 0; rt < 2; rt++) {
#pragma unroll
            for (int ks = 0; ks < 4; ks++) {
                acc[rt][t] = __builtin_amdgcn_mfma_f32_16x16x32_bf16(
                    xf[rt][ks], bb[ks], acc[rt][t], 0, 0, 0);
                acc[rt][t] = __builtin_amdgcn_mfma_f32_16x16x32_bf16(
                    af[rt][ks], ba[ks], acc[rt][t], 0, 0, 0);
            }
        }
    }

#pragma unroll
    for (int rt = 0; rt < 2; rt++)
#pragma unroll
        for (int r = 0; r < 4; r++) {
            long long row = rowbase + rt * 16 + kg * 4 + r;
            if (row < N)
#pragma unroll
                for (int t = 0; t < 8; t++)
                    H[(size_t)t * NN16 + (size_t)row * 16 + r16] =
                        f2bf(fmaxf(acc[rt][t][r], 0.f));
        }
}

// ---------------------------------------------------------------------------
// GEMM 2+3 fused dual-output (W-in-LDS): t2 = h@W_l2 (blocked out),
// p3 = h@W_r2 + b2 (row-major out). h fragments read once.
// ---------------------------------------------------------------------------
__global__ __launch_bounds__(256) void gemm23_kernel(
    const unsigned short* __restrict__ Hb,  // blocked [8][NN][16]
    const float* __restrict__ Wl,           // W_l2 [128][64] f32
    const float* __restrict__ Wr,           // W_r2 [128][64] f32
    const float* __restrict__ b2,
    unsigned short* __restrict__ T2,        // blocked [4][NN][16]
    unsigned short* __restrict__ P3,        // row-major [NN][64]
    int N) {
    constexpr int PITCH = 136;
    __shared__ unsigned short sWl[64 * PITCH];
    __shared__ unsigned short sWr[64 * PITCH];
    const int tid = threadIdx.x;
    for (int idx = tid; idx < 128 * 64; idx += 256) {
        int k = idx >> 6, n = idx & 63;
        sWl[n * PITCH + k] = f2bf(Wl[idx]);
        sWr[n * PITCH + k] = f2bf(Wr[idx]);
    }
    __syncthreads();

    const int lane = tid & 63;
    const int wv = tid >> 6;
    const int r16 = lane & 15;
    const int kg = lane >> 4;
    const long long rowbase = (long long)blockIdx.x * 128 + wv * 32;

    bf16x8 hf[2][4];
    const bf16x8 zz = {0, 0, 0, 0, 0, 0, 0, 0};
#pragma unroll
    for (int rt = 0; rt < 2; rt++) {
        long long row = rowbase + rt * 16 + r16;
        bool ok = row < N;
#pragma unroll
        for (int ks = 0; ks < 4; ks++) {
            size_t off = (size_t)(2 * ks + (kg >> 1)) * NN16 + (size_t)row * 16 + (kg & 1) * 8;
            hf[rt][ks] = ok ? *(const bf16x8*)(Hb + off) : zz;
        }
    }

    f32x4 ot[2][4], op[2][4];
#pragma unroll
    for (int t = 0; t < 4; t++) {
        float bv = b2[t * 16 + r16];
#pragma unroll
        for (int rt = 0; rt < 2; rt++) {
            ot[rt][t] = (f32x4){0.f, 0.f, 0.f, 0.f};
            op[rt][t] = (f32x4){bv, bv, bv, bv};
        }
    }

#pragma unroll
    for (int t = 0; t < 4; t++) {
        const unsigned short* wl = &sWl[(t * 16 + r16) * PITCH + kg * 8];
        const unsigned short* wr = &sWr[(t * 16 + r16) * PITCH + kg * 8];
        bf16x8 bl[4], br[4];
#pragma unroll
        for (int ks = 0; ks < 4; ks++) {
            bl[ks] = *(const bf16x8*)(wl + ks * 32);
            br[ks] = *(const bf16x8*)(wr + ks * 32);
        }
#pragma unroll
        for (int rt = 0; rt < 2; rt++) {
#pragma unroll
            for (int ks = 0; ks < 4; ks++) {
                ot[rt][t] = __builtin_amdgcn_mfma_f32_16x16x32_bf16(
                    hf[rt][ks], bl[ks], ot[rt][t], 0, 0, 0);
                op[rt][t] = __builtin_amdgcn_mfma_f32_16x16x32_bf16(
                    hf[rt][ks], br[ks], op[rt][t], 0, 0, 0);
            }
        }
    }

#pragma unroll
    for (int rt = 0; rt < 2; rt++)
#pragma unroll
        for (int r = 0; r < 4; r++) {
            long long row = rowbase + rt * 16 + kg * 4 + r;
            if (row < N)
#pragma unroll
                for (int t = 0; t < 4; t++) {
                    T2[(size_t)t * NN16 + (size_t)row * 16 + r16] = f2bf(ot[rt][t][r]);
                    P3[(size_t)row * 64 + t * 16 + r16] = f2bf(op[rt][t][r]);
                }
        }
}

// ---------------------------------------------------------------------------
// Column-blocked fused layer-2 tail: out = mean_nb(t2) + p3, f32 row-major.
// t2 is [4][NN][16]; xcd = blockIdx&7 -> (colgroup g2 = xcd>>1, node half =
// xcd&1): each XCD's slice = 3.2MB (L2-resident). 8 lanes/node as gather128.
// ---------------------------------------------------------------------------
__global__ __launch_bounds__(256) void gather2_col(
    const unsigned short* __restrict__ t2, const unsigned short* __restrict__ p3,
    const int* __restrict__ csr, const int* __restrict__ S, float* __restrict__ out) {
    const int xcd = blockIdx.x & 7;
    const int g2 = xcd >> 1;
    const int nh = xcd & 1;
    const int q = blockIdx.x >> 3;
    const int lane8 = threadIdx.x & 7;
    const int node = nh * (NN / 2) + q * 32 + (threadIdx.x >> 3);
    if (node >= nh * (NN / 2) + (NN / 2)) return;
    const int half = lane8 & 1;
    const int slot = lane8 >> 1;
    const int begin = S[node];
    const int end = (node == NN - 1) ? NE : S[node + 1];
    const unsigned short* base = t2 + (size_t)g2 * NN16 + half * 8;
    float acc0[8] = {0.f, 0.f, 0.f, 0.f, 0.f, 0.f, 0.f, 0.f};
    float acc1[8] = {0.f, 0.f, 0.f, 0.f, 0.f, 0.f, 0.f, 0.f};
    int j = begin + slot;
    for (; j + 4 < end; j += 8) {
        int s0 = __builtin_nontemporal_load(csr + j);
        int s1 = __builtin_nontemporal_load(csr + j + 4);
        bf16x8 v0 = *(const bf16x8*)(base + (size_t)s0 * 16);
        bf16x8 v1 = *(const bf16x8*)(base + (size_t)s1 * 16);
#pragma unroll
        for (int p = 0; p < 8; p++) {
            acc0[p] += bf2f((unsigned short)v0[p]);
            acc1[p] += bf2f((unsigned short)v1[p]);
        }
    }
    if (j < end) {
        int s = __builtin_nontemporal_load(csr + j);
        bf16x8 v = *(const bf16x8*)(base + (size_t)s * 16);
#pragma unroll
        for (int p = 0; p < 8; p++) acc0[p] += bf2f((unsigned short)v[p]);
    }
#pragma unroll
    for (int p = 0; p < 8; p++) {
        float a = acc0[p] + acc1[p];
        a += __shfl_xor(a, 2, 64);
        a += __shfl_xor(a, 4, 64);
        acc0[p] = a;
    }
    if (slot == 0) {
        const float inv = 1.0f / fmaxf((float)(end - begin), 1.0f);
        const bf16x8 pv = __builtin_nontemporal_load(
            (const bf16x8*)(p3 + (size_t)node * 64 + g2 * 16 + half * 8));
        f32x4 r0, r1;
#pragma unroll
        for (int p = 0; p < 4; p++) {
            r0[p] = acc0[p] * inv + bf2f((unsigned short)pv[p]);
            r1[p] = acc0[4 + p] * inv + bf2f((unsigned short)pv[4 + p]);
        }
        float* o = out + (size_t)node * 64 + g2 * 16 + half * 8;
        __builtin_nontemporal_store(r0, (f32x4*)o);
        __builtin_nontemporal_store(r1, (f32x4*)(o + 4));
    }
}

extern "C" void kernel_launch(void* const* d_in, const int* in_sizes, int n_in,
                              void* d_out, int out_size, void* d_ws, size_t ws_size,
                              hipStream_t stream) {
    const float* x    = (const float*)d_in[0];
    const int*   e32  = (const int*)d_in[1];
    const float* W_l1 = (const float*)d_in[2];
    const float* W_r1 = (const float*)d_in[3];
    const float* b1   = (const float*)d_in[4];
    const float* W_l2 = (const float*)d_in[5];
    const float* W_r2 = (const float*)d_in[6];
    const float* b2   = (const float*)d_in[7];
    float* out = (float*)d_out;

    // Workspace map (int offsets):
    //   flag 0 | S 1024(+100352) | part 101376(+512) | csr 101888(+1.6M)
    //   xb 1701888(+6.4M) [t2b overlays first 3.2M, p3b next 3.2M after gemm1]
    //   G/mean1b 8101888(+6.4M) | hb 14524416(+6.4M) -> ends 20,924,416 (~84MB)
    int* wsI = (int*)d_ws;
    int* flag = wsI;
    int* S    = wsI + 1024;
    int* part = wsI + 101376;
    int* csr  = wsI + 101888;
    unsigned short* xb  = (unsigned short*)(wsI + 1701888);
    unsigned short* t2b = (unsigned short*)(wsI + 1701888);     // [4][NN][16]
    unsigned short* p3b = (unsigned short*)(wsI + 4901888);     // [NN][64]
    int* G = wsI + 8101888;
    unsigned short* mean1b = (unsigned short*)(wsI + 8101888);  // [8][NN][16]
    unsigned short* hb     = (unsigned short*)(wsI + 14524416); // [8][NN][16]

    hipMemsetAsync(d_ws, 0, 4096, stream);  // flag

    detect_kernel<<<16, 256, 0, stream>>>(e32, flag);
    histA_kernel<<<NRANGE * NCHUNK, 1024, 0, stream>>>(e32, flag, G);
    prefix_cvt_kernel<<<PREF_B + CVT_G, 256, 0, stream>>>(G, S, x, xb);
    blocksum_kernel<<<SCAN_G, 256, 0, stream>>>(S, part);
    partscan_kernel<<<1, 512, 0, stream>>>(part);
    scanfin_kernel<<<SCAN_G, 256, 0, stream>>>(S, part);
    scatterC_kernel<<<NRANGE * NCHUNK, 1024, 0, stream>>>(e32, flag, S, G, csr);

    // mean1 = mean_neighbors(x)   (col-blocked, XCD-pinned slices)
    gather128_col<<<3125 * 8, 256, 0, stream>>>(xb, csr, S, mean1b);

    // h = relu(mean1@W_l1 + x@W_r1 + b1)
    gemm1_kernel<<<782, 256, 0, stream>>>(mean1b, xb, W_l1, W_r1, b1, hb, NN);

    // t2 = h@W_l2 (blocked) ; p3 = h@W_r2 + b2   (t2b/p3b overlay dead xb)
    gemm23_kernel<<<782, 256, 0, stream>>>(hb, W_l2, W_r2, b2, t2b, p3b, NN);

    // out = mean_neighbors(t2) + p3
    gather2_col<<<1563 * 8, 256, 0, stream>>>(t2b, p3b, csr, S, out);
}

// Round 15
// 197.874 us; speedup vs baseline: 1.5212x; 1.5212x over previous
//
#include <hip/hip_runtime.h>

#define NN 100000
#define NE 1600000
// DIM_IN = DIM_H = 128, DIM_OUT = 64

typedef __attribute__((ext_vector_type(8))) short bf16x8;   // 8 bf16 = 4 VGPR
typedef __attribute__((ext_vector_type(4))) float f32x4;

__device__ __forceinline__ float bf2f(unsigned short b) {
    union { unsigned int u; float f; } v;
    v.u = ((unsigned int)b) << 16;
    return v.f;
}
__device__ __forceinline__ unsigned short f2bf(float f) {
    union { float f; unsigned int u; } v; v.f = f;
    unsigned int u = v.u;
    return (unsigned short)((u + 0x7FFFu + ((u >> 16) & 1u)) >> 16);  // RNE
}

// ---------------------------------------------------------------------------
// edge_index dtype detect: int64 -> high words all 0; int32 -> odd words are
// random node ids (nonzero w.p. ~1). flag: 0 = int64, 1 = int32.
// ---------------------------------------------------------------------------
__global__ void detect_kernel(const int* __restrict__ e, int* __restrict__ flag) {
    int t = blockIdx.x * blockDim.x + threadIdx.x;
    if (t < 4096 && e[2 * t + 1] != 0) atomicOr(flag, 1);
}

__device__ __forceinline__ int esrc(const int* e, int mode, int i) {
    return mode ? e[i] : e[2 * i];
}
__device__ __forceinline__ int edst(const int* e, int mode, int i) {
    return mode ? e[NE + i] : e[2 * (NE + i)];
}

// ---------------------------------------------------------------------------
// W pre-transpose+cvt: wt = { W_l1^T[128][128], W_r1^T[128][128],
// W_l2^T[64][128], W_r2^T[64][128] } bf16 (96KB, L2-hot). Verified in r13.
// ---------------------------------------------------------------------------
__global__ __launch_bounds__(256) void wcvt_kernel(
    const float* __restrict__ W_l1, const float* __restrict__ W_r1,
    const float* __restrict__ W_l2, const float* __restrict__ W_r2,
    unsigned short* __restrict__ wt) {
    int b = blockIdx.x;
    const float* src; unsigned short* dst; int NO, tk, tn;
    if (b < 4)       { src = W_l1; dst = wt;         NO = 128; tk = b >> 1; tn = b & 1; }
    else if (b < 8)  { b -= 4; src = W_r1; dst = wt + 16384; NO = 128; tk = b >> 1; tn = b & 1; }
    else if (b < 10) { b -= 8; src = W_l2; dst = wt + 32768; NO = 64; tk = b; tn = 0; }
    else             { b -= 10; src = W_r2; dst = wt + 40960; NO = 64; tk = b; tn = 0; }
    __shared__ unsigned short lt[64][72];
    const int r0 = tk * 64, c0 = tn * 64;
    const int lr = threadIdx.x >> 6;   // 0..3
    const int lc = threadIdx.x & 63;
#pragma unroll
    for (int i = 0; i < 16; i++) {
        int r = lr * 16 + i;
        lt[lc][r] = f2bf(src[(size_t)(r0 + r) * NO + c0 + lc]);  // transpose in LDS
    }
    __syncthreads();
#pragma unroll
    for (int i = 0; i < 16; i++) {
        int n = lr * 16 + i;
        dst[(size_t)(c0 + n) * 128 + r0 + lc] = lt[n][lc];
    }
}

// ---------------------------------------------------------------------------
// LDS counting-sort CSR build (zero global atomics). Block (r,c) = dst-range r
// (25000 nodes, 100KB LDS) x edge-chunk c. Pass A: LDS hist -> G[c][d].
// Pass C: re-scan chunk, scatter via csr[atomicAdd(&sOff[dl],1)], sOff = S+G.
// ---------------------------------------------------------------------------
#define NRANGE 4
#define RSZ 25000
#define NCHUNK 64
#define EPC (NE / NCHUNK)
#define GS 100352

__global__ __launch_bounds__(1024) void histA_kernel(
    const int* __restrict__ e, const int* __restrict__ flag, int* __restrict__ G) {
    __shared__ int lh[RSZ];
    const int bid = blockIdx.x;
    const int r = bid & (NRANGE - 1);
    const int c = bid >> 2;
    const int lo = r * RSZ;
    for (int idx = threadIdx.x; idx < RSZ; idx += 1024) lh[idx] = 0;
    __syncthreads();
    const int mode = *flag;
    const int base = c * EPC;
    for (int i = base + threadIdx.x; i < base + EPC; i += 1024) {
        int dl = edst(e, mode, i) - lo;
        if ((unsigned)dl < (unsigned)RSZ) atomicAdd(&lh[dl], 1);
    }
    __syncthreads();
    for (int idx = threadIdx.x; idx < RSZ; idx += 1024)
        G[(size_t)c * GS + lo + idx] = lh[idx];
}

__global__ __launch_bounds__(1024) void scatterC_kernel(
    const int* __restrict__ e, const int* __restrict__ flag,
    const int* __restrict__ S, const int* __restrict__ G, int* __restrict__ csr) {
    __shared__ int sOff[RSZ];
    const int bid = blockIdx.x;
    const int r = bid & (NRANGE - 1);
    const int c = bid >> 2;
    const int lo = r * RSZ;
    for (int idx = threadIdx.x; idx < RSZ; idx += 1024)
        sOff[idx] = S[lo + idx] + G[(size_t)c * GS + lo + idx];
    __syncthreads();
    const int mode = *flag;
    const int base = c * EPC;
    for (int i = base + threadIdx.x; i < base + EPC; i += 1024) {
        int dl = edst(e, mode, i) - lo;
        if ((unsigned)dl < (unsigned)RSZ) {
            int s = esrc(e, mode, i);
            csr[atomicAdd(&sOff[dl], 1)] = s;
        }
    }
}

// ---------------------------------------------------------------------------
// Kernel B: per-node exclusive prefix of G over the 64 chunks (in place),
// deg -> S. f32->bf16 convert of x fused into the same grid (independent).
// ---------------------------------------------------------------------------
#define PREF_B 391
#define CVT_G 6250

__global__ __launch_bounds__(256) void prefix_cvt_kernel(
    int* __restrict__ G, int* __restrict__ S,
    const float* __restrict__ xin, unsigned short* __restrict__ xb) {
    if (blockIdx.x < PREF_B) {
        int d = blockIdx.x * 256 + threadIdx.x;
        if (d >= NN) return;
        int run = 0;
#pragma unroll 8
        for (int c = 0; c < NCHUNK; c++) {
            size_t idx = (size_t)c * GS + d;
            int t = G[idx];
            G[idx] = run;
            run += t;
        }
        S[d] = run;  // in-degree
    } else {
        long long i = ((long long)(blockIdx.x - PREF_B) * 256 + threadIdx.x) * 8;
        float4 a = *(const float4*)(xin + i);
        float4 b = *(const float4*)(xin + i + 4);
        bf16x8 rv;
        rv[0] = (short)f2bf(a.x); rv[1] = (short)f2bf(a.y);
        rv[2] = (short)f2bf(a.z); rv[3] = (short)f2bf(a.w);
        rv[4] = (short)f2bf(b.x); rv[5] = (short)f2bf(b.y);
        rv[6] = (short)f2bf(b.z); rv[7] = (short)f2bf(b.w);
        *(bf16x8*)(xb + i) = rv;
    }
}

// ---------------------------------------------------------------------------
// 3-phase exclusive scan of S[0..NN). S becomes the global exclusive prefix.
// ---------------------------------------------------------------------------
#define SCAN_G 392

__global__ __launch_bounds__(256) void blocksum_kernel(const int* __restrict__ S,
                                                       int* __restrict__ part) {
    int i = blockIdx.x * 256 + threadIdx.x;
    int v = (i < NN) ? S[i] : 0;
#pragma unroll
    for (int off = 32; off; off >>= 1) v += __shfl_down(v, off, 64);
    __shared__ int wsum[4];
    if ((threadIdx.x & 63) == 0) wsum[threadIdx.x >> 6] = v;
    __syncthreads();
    if (threadIdx.x == 0)
        part[blockIdx.x] = wsum[0] + wsum[1] + wsum[2] + wsum[3];
}

__global__ __launch_bounds__(512) void partscan_kernel(int* __restrict__ part) {
    __shared__ int lds[512];
    const int t = threadIdx.x;
    int v = (t < SCAN_G) ? part[t] : 0;
    lds[t] = v;
    __syncthreads();
    for (int off = 1; off < 512; off <<= 1) {
        int u = (t >= off) ? lds[t - off] : 0;
        __syncthreads();
        lds[t] += u;
        __syncthreads();
    }
    if (t < SCAN_G) part[t] = lds[t] - v;  // exclusive
}

__global__ __launch_bounds__(256) void scanfin_kernel(int* __restrict__ S,
                                                      const int* __restrict__ part) {
    __shared__ int lds[256];
    const int t = threadIdx.x;
    const int i = blockIdx.x * 256 + t;
    int v = (i < NN) ? S[i] : 0;
    lds[t] = v;
    __syncthreads();
    for (int off = 1; off < 256; off <<= 1) {
        int u = (t >= off) ? lds[t - off] : 0;
        __syncthreads();
        lds[t] += u;
        __syncthreads();
    }
    if (i < NN) S[i] = lds[t] - v + part[blockIdx.x];  // exclusive + block offset
}

// ---------------------------------------------------------------------------
// gather-mean over CSR (D=128), bf16 in/out, f32 accumulate. 16 lanes/node,
// 4-deep MLP unroll (proven fastest: r9/r13 = 58µs).
// ---------------------------------------------------------------------------
__global__ __launch_bounds__(256) void gather_mean128(
    const unsigned short* __restrict__ feat, const int* __restrict__ csr,
    const int* __restrict__ S, unsigned short* __restrict__ out) {
    const int tid = threadIdx.x;
    const int node = blockIdx.x * 16 + (tid >> 4);
    const int c = tid & 15;
    if (node >= NN) return;
    const int begin = S[node];
    const int end = (node == NN - 1) ? NE : S[node + 1];
    float acc0[8] = {0.f, 0.f, 0.f, 0.f, 0.f, 0.f, 0.f, 0.f};
    float acc1[8] = {0.f, 0.f, 0.f, 0.f, 0.f, 0.f, 0.f, 0.f};
    int j = begin;
    for (; j + 4 <= end; j += 4) {
        int s0 = csr[j], s1 = csr[j + 1], s2 = csr[j + 2], s3 = csr[j + 3];
        bf16x8 v0 = *(const bf16x8*)(feat + (size_t)s0 * 128 + 8 * c);
        bf16x8 v1 = *(const bf16x8*)(feat + (size_t)s1 * 128 + 8 * c);
        bf16x8 v2 = *(const bf16x8*)(feat + (size_t)s2 * 128 + 8 * c);
        bf16x8 v3 = *(const bf16x8*)(feat + (size_t)s3 * 128 + 8 * c);
#pragma unroll
        for (int q = 0; q < 8; q++) {
            acc0[q] += bf2f((unsigned short)v0[q]) + bf2f((unsigned short)v2[q]);
            acc1[q] += bf2f((unsigned short)v1[q]) + bf2f((unsigned short)v3[q]);
        }
    }
    for (; j < end; j++) {
        int s = csr[j];
        bf16x8 v = *(const bf16x8*)(feat + (size_t)s * 128 + 8 * c);
#pragma unroll
        for (int q = 0; q < 8; q++) acc0[q] += bf2f((unsigned short)v[q]);
    }
    const float inv = 1.0f / fmaxf((float)(end - begin), 1.0f);
    bf16x8 r;
#pragma unroll
    for (int q = 0; q < 8; q++) r[q] = (short)f2bf((acc0[q] + acc1[q]) * inv);
    *(bf16x8*)(out + (size_t)node * 128 + 8 * c) = r;
}

// ---------------------------------------------------------------------------
// Mega GEMM (r11 structure + vector W staging): h = relu(mean1@W_l1 +
// x@W_r1 + b1) per wave-tile, round-tripped through LDS only; epilogue
// restages W_l2^T|W_r2^T and emits t2 = h@W_l2, p3 = h@W_r2 + b2.
// All W staged from PRE-TRANSPOSED bf16 W^T via 16B vector copies (16
// iters/thread vs 384 scalar f32+f2bf+2B-write in r11 — the 8-way-conflict
// prologue that held mega at 58.6µs / MfmaUtil 6%).
// C/D layout: col=lane&15, row=(lane>>4)*4+reg.
// ---------------------------------------------------------------------------
__global__ __launch_bounds__(256, 2) void mega_gemm(
    const unsigned short* __restrict__ A,     // mean1b [N,128] bf16
    const unsigned short* __restrict__ X,     // xb [N,128] bf16
    const unsigned short* __restrict__ WaT,   // W_l1^T [128][128] bf16
    const unsigned short* __restrict__ WbT,   // W_r1^T [128][128] bf16
    const float* __restrict__ b1,
    const unsigned short* __restrict__ WlT,   // W_l2^T [64][128] bf16
    const unsigned short* __restrict__ WrT,   // W_r2^T [64][128] bf16
    const float* __restrict__ b2,
    unsigned short* __restrict__ T2, unsigned short* __restrict__ P3, int N) {
    constexpr int PITCH = 136;
    __shared__ unsigned short sWb[128 * PITCH];  // W_r1^T, then per-wave h tiles
    __shared__ unsigned short sWa[128 * PITCH];  // W_l1^T, then W_l2^T | W_r2^T

    const int tid = threadIdx.x;
    for (int idx = tid; idx < 128 * 16; idx += 256) {
        int n = idx >> 4, ch = (idx & 15) * 8;
        *(bf16x8*)&sWa[n * PITCH + ch] = *(const bf16x8*)(WaT + (size_t)n * 128 + ch);
        *(bf16x8*)&sWb[n * PITCH + ch] = *(const bf16x8*)(WbT + (size_t)n * 128 + ch);
    }
    __syncthreads();

    const int lane = tid & 63;
    const int wv = tid >> 6;
    const int r16 = lane & 15;
    const int kg = lane >> 4;
    const long long rowbase = (long long)blockIdx.x * 128 + wv * 32;

    bf16x8 xf[2][4], af[2][4];
    const bf16x8 zz = {0, 0, 0, 0, 0, 0, 0, 0};
#pragma unroll
    for (int rt = 0; rt < 2; rt++) {
        long long row = rowbase + rt * 16 + r16;
        bool ok = row < N;
#pragma unroll
        for (int ks = 0; ks < 4; ks++) {
            xf[rt][ks] = ok ? *(const bf16x8*)(X + row * 128 + ks * 32 + kg * 8) : zz;
            af[rt][ks] = ok ? *(const bf16x8*)(A + row * 128 + ks * 32 + kg * 8) : zz;
        }
    }

    f32x4 acc[2][8];
#pragma unroll
    for (int t = 0; t < 8; t++) {
        float bv = b1[t * 16 + r16];
#pragma unroll
        for (int rt = 0; rt < 2; rt++) acc[rt][t] = (f32x4){bv, bv, bv, bv};
    }

#pragma unroll
    for (int t = 0; t < 8; t++) {
        const unsigned short* wp = &sWb[(t * 16 + r16) * PITCH + kg * 8];
        const unsigned short* wq = &sWa[(t * 16 + r16) * PITCH + kg * 8];
        bf16x8 bb[4], ba[4];
#pragma unroll
        for (int ks = 0; ks < 4; ks++) {
            bb[ks] = *(const bf16x8*)(wp + ks * 32);
            ba[ks] = *(const bf16x8*)(wq + ks * 32);
        }
#pragma unroll
        for (int rt = 0; rt < 2; rt++) {
#pragma unroll
            for (int ks = 0; ks < 4; ks++) {
                acc[rt][t] = __builtin_amdgcn_mfma_f32_16x16x32_bf16(
                    xf[rt][ks], bb[ks], acc[rt][t], 0, 0, 0);
                acc[rt][t] = __builtin_amdgcn_mfma_f32_16x16x32_bf16(
                    af[rt][ks], ba[ks], acc[rt][t], 0, 0, 0);
            }
        }
    }

    __syncthreads();  // all waves done reading W_l1/W_r1

    // restage W_l2^T | W_r2^T into sWa (16B copies)
    for (int idx = tid; idx < 64 * 16; idx += 256) {
        int n = idx >> 4, ch = (idx & 15) * 8;
        *(bf16x8*)&sWa[n * PITCH + ch] = *(const bf16x8*)(WlT + (size_t)n * 128 + ch);
        *(bf16x8*)&sWa[(64 + n) * PITCH + ch] = *(const bf16x8*)(WrT + (size_t)n * 128 + ch);
    }
    // write own h tile (relu'd bf16) into this wave's sWb region
    unsigned short* sh = sWb + wv * 32 * PITCH;
#pragma unroll
    for (int rt = 0; rt < 2; rt++)
#pragma unroll
        for (int t = 0; t < 8; t++)
#pragma unroll
            for (int r = 0; r < 4; r++)
                sh[(rt * 16 + kg * 4 + r) * PITCH + t * 16 + r16] =
                    f2bf(fmaxf(acc[rt][t][r], 0.f));
    __syncthreads();

    // h A-fragments from own LDS tile
    bf16x8 hf[2][4];
#pragma unroll
    for (int rt = 0; rt < 2; rt++)
#pragma unroll
        for (int ks = 0; ks < 4; ks++)
            hf[rt][ks] = *(const bf16x8*)(sh + (rt * 16 + r16) * PITCH + ks * 32 + kg * 8);

    // t2 = h @ W_l2
    {
        f32x4 o[2][4];
#pragma unroll
        for (int t = 0; t < 4; t++)
#pragma unroll
            for (int rt = 0; rt < 2; rt++) o[rt][t] = (f32x4){0.f, 0.f, 0.f, 0.f};
#pragma unroll
        for (int t = 0; t < 4; t++) {
            const unsigned short* wp = &sWa[(t * 16 + r16) * PITCH + kg * 8];
            bf16x8 bb[4];
#pragma unroll
            for (int ks = 0; ks < 4; ks++) bb[ks] = *(const bf16x8*)(wp + ks * 32);
#pragma unroll
            for (int rt = 0; rt < 2; rt++)
#pragma unroll
                for (int ks = 0; ks < 4; ks++)
                    o[rt][t] = __builtin_amdgcn_mfma_f32_16x16x32_bf16(
                        hf[rt][ks], bb[ks], o[rt][t], 0, 0, 0);
        }
#pragma unroll
        for (int rt = 0; rt < 2; rt++)
#pragma unroll
            for (int r = 0; r < 4; r++) {
                long long row = rowbase + rt * 16 + kg * 4 + r;
                if (row < N)
#pragma unroll
                    for (int t = 0; t < 4; t++)
                        T2[row * 64 + t * 16 + r16] = f2bf(o[rt][t][r]);
            }
    }
    // p3 = h @ W_r2 + b2
    {
        f32x4 o[2][4];
#pragma unroll
        for (int t = 0; t < 4; t++) {
            float bv = b2[t * 16 + r16];
#pragma unroll
            for (int rt = 0; rt < 2; rt++) o[rt][t] = (f32x4){bv, bv, bv, bv};
        }
#pragma unroll
        for (int t = 0; t < 4; t++) {
            const unsigned short* wp = &sWa[(64 + t * 16 + r16) * PITCH + kg * 8];
            bf16x8 bb[4];
#pragma unroll
            for (int ks = 0; ks < 4; ks++) bb[ks] = *(const bf16x8*)(wp + ks * 32);
#pragma unroll
            for (int rt = 0; rt < 2; rt++)
#pragma unroll
                for (int ks = 0; ks < 4; ks++)
                    o[rt][t] = __builtin_amdgcn_mfma_f32_16x16x32_bf16(
                        hf[rt][ks], bb[ks], o[rt][t], 0, 0, 0);
        }
#pragma unroll
        for (int rt = 0; rt < 2; rt++)
#pragma unroll
            for (int r = 0; r < 4; r++) {
                long long row = rowbase + rt * 16 + kg * 4 + r;
                if (row < N)
#pragma unroll
                    for (int t = 0; t < 4; t++)
                        P3[row * 64 + t * 16 + r16] = f2bf(o[rt][t][r]);
            }
    }
}

// ---------------------------------------------------------------------------
// Fused layer-2 tail: out[node] = mean_neighbors(t2) + p3[node], f32 output.
// 8 lanes/node, 4-deep MLP unroll.
// ---------------------------------------------------------------------------
__global__ __launch_bounds__(256) void gather2_fused(
    const unsigned short* __restrict__ t2, const unsigned short* __restrict__ p3,
    const int* __restrict__ csr, const int* __restrict__ S, float* __restrict__ out) {
    const int tid = threadIdx.x;
    const int node = blockIdx.x * 32 + (tid >> 3);
    const int c = tid & 7;
    if (node >= NN) return;
    const int begin = S[node];
    const int end = (node == NN - 1) ? NE : S[node + 1];
    float acc0[8] = {0.f, 0.f, 0.f, 0.f, 0.f, 0.f, 0.f, 0.f};
    float acc1[8] = {0.f, 0.f, 0.f, 0.f, 0.f, 0.f, 0.f, 0.f};
    int j = begin;
    for (; j + 4 <= end; j += 4) {
        int s0 = csr[j], s1 = csr[j + 1], s2 = csr[j + 2], s3 = csr[j + 3];
        bf16x8 v0 = *(const bf16x8*)(t2 + (size_t)s0 * 64 + 8 * c);
        bf16x8 v1 = *(const bf16x8*)(t2 + (size_t)s1 * 64 + 8 * c);
        bf16x8 v2 = *(const bf16x8*)(t2 + (size_t)s2 * 64 + 8 * c);
        bf16x8 v3 = *(const bf16x8*)(t2 + (size_t)s3 * 64 + 8 * c);
#pragma unroll
        for (int q = 0; q < 8; q++) {
            acc0[q] += bf2f((unsigned short)v0[q]) + bf2f((unsigned short)v2[q]);
            acc1[q] += bf2f((unsigned short)v1[q]) + bf2f((unsigned short)v3[q]);
        }
    }
    for (; j < end; j++) {
        int s = csr[j];
        bf16x8 v = *(const bf16x8*)(t2 + (size_t)s * 64 + 8 * c);
#pragma unroll
        for (int q = 0; q < 8; q++) acc0[q] += bf2f((unsigned short)v[q]);
    }
    const float inv = 1.0f / fmaxf((float)(end - begin), 1.0f);
    bf16x8 pv = *(const bf16x8*)(p3 + (size_t)node * 64 + 8 * c);
    f32x4 r0, r1;
#pragma unroll
    for (int q = 0; q < 4; q++) {
        r0[q] = (acc0[q] + acc1[q]) * inv + bf2f((unsigned short)pv[q]);
        r1[q] = (acc0[4 + q] + acc1[4 + q]) * inv + bf2f((unsigned short)pv[4 + q]);
    }
    *(f32x4*)(out + (size_t)node * 64 + 8 * c) = r0;
    *(f32x4*)(out + (size_t)node * 64 + 8 * c + 4) = r1;
}

extern "C" void kernel_launch(void* const* d_in, const int* in_sizes, int n_in,
                              void* d_out, int out_size, void* d_ws, size_t ws_size,
                              hipStream_t stream) {
    const float* x    = (const float*)d_in[0];
    const int*   e32  = (const int*)d_in[1];
    const float* W_l1 = (const float*)d_in[2];
    const float* W_r1 = (const float*)d_in[3];
    const float* b1   = (const float*)d_in[4];
    const float* W_l2 = (const float*)d_in[5];
    const float* W_r2 = (const float*)d_in[6];
    const float* b2   = (const float*)d_in[7];
    float* out = (float*)d_out;

    // Workspace map (int offsets) — identical to r11 (passed) + wt at the end:
    //   flag 0 | S 1024(+100352) | part 101376(+512) | csr 101888(+1.6M)
    //   xb 1701888(+6.4M) | G/mean1b 8101888(+6.4M) | t2b 14524416(+3.2M)
    //   p3b 17724416(+3.2M) | wt 20924416(+12288) -> ends ~83.7MB
    int* wsI = (int*)d_ws;
    int* flag = wsI;
    int* S    = wsI + 1024;
    int* part = wsI + 101376;
    int* csr  = wsI + 101888;
    unsigned short* xb = (unsigned short*)(wsI + 1701888);       // [NN*128]
    int* G = wsI + 8101888;                                      // [64*100352]
    unsigned short* mean1b = (unsigned short*)(wsI + 8101888);   // [NN*128]
    unsigned short* t2b    = (unsigned short*)(wsI + 14524416);  // [NN*64]
    unsigned short* p3b    = (unsigned short*)(wsI + 17724416);  // [NN*64]
    unsigned short* wt     = (unsigned short*)(wsI + 20924416);  // [49152 bf16]

    hipMemsetAsync(d_ws, 0, 4096, stream);  // flag

    detect_kernel<<<16, 256, 0, stream>>>(e32, flag);
    wcvt_kernel<<<12, 256, 0, stream>>>(W_l1, W_r1, W_l2, W_r2, wt);
    histA_kernel<<<NRANGE * NCHUNK, 1024, 0, stream>>>(e32, flag, G);
    prefix_cvt_kernel<<<PREF_B + CVT_G, 256, 0, stream>>>(G, S, x, xb);
    blocksum_kernel<<<SCAN_G, 256, 0, stream>>>(S, part);
    partscan_kernel<<<1, 512, 0, stream>>>(part);
    scanfin_kernel<<<SCAN_G, 256, 0, stream>>>(S, part);
    scatterC_kernel<<<NRANGE * NCHUNK, 1024, 0, stream>>>(e32, flag, S, G, csr);

    // mean1 = mean_neighbors(x)
    gather_mean128<<<6250, 256, 0, stream>>>(xb, csr, S, mean1b);

    // h (LDS-only) -> t2 = h@W_l2, p3 = h@W_r2 + b2
    mega_gemm<<<782, 256, 0, stream>>>(mean1b, xb, wt, wt + 16384, b1,
                                       wt + 32768, wt + 40960, b2, t2b, p3b, NN);

    // out = mean_neighbors(t2) + p3
    gather2_fused<<<3125, 256, 0, stream>>>(t2b, p3b, csr, S, out);
}